// Round 7
// baseline (503.647 us; speedup 1.0000x reference)
//
#include <hip/hip_runtime.h>
#include <stdint.h>

typedef __attribute__((ext_vector_type(4))) float f32x4;
typedef __attribute__((ext_vector_type(8))) short short8;

#define NROWS 8192

static __device__ __forceinline__ unsigned int f2bf(float f) {
  unsigned int u = __float_as_uint(f);
  return (u + 0x7fffu + ((u >> 16) & 1u)) >> 16;  // RNE
}
static __device__ __forceinline__ float bf2f(unsigned int h) {
  return __uint_as_float(h << 16);
}
static __device__ __forceinline__ float fast_exp2(float x) {
  // args bounded (|x| < 3): raw v_exp_f32, skip OCML range/denorm handling
#if __has_builtin(__builtin_amdgcn_exp2f)
  return __builtin_amdgcn_exp2f(x);
#else
  float r;
  asm("v_exp_f32 %0, %1" : "=v"(r) : "v"(x));
  return r;
#endif
}

// hs layout: per 256B row r, 16B chunk c stored at chunk position c ^ (r&7).
// Linear global->LDS DMA then yields the bank-conflict-free swizzled LDS
// layout for ds_read_b128 fragments (G4 / m201 pre-swizzled-source pattern).

// ---------------------------------------------------------------------------
// Kernel 1: projection fc2(elu(fc1(z))) + L2-normalize, bf16 MFMA + f32
// epilogue. 256 blocks x 256 threads; block = 64 rows of one z. Output rows
// pre-scaled by sqrt(2*log2 e) so Gram MFMA output is the exp2 argument,
// written in the swizzled global layout.
// ---------------------------------------------------------------------------
__global__ __launch_bounds__(256) void proj_kernel(
    const float* __restrict__ z1, const float* __restrict__ z2,
    const float* __restrict__ w1g, const float* __restrict__ b1g,
    const float* __restrict__ w2g, const float* __restrict__ b2g,
    unsigned short* __restrict__ hs1, unsigned short* __restrict__ hs2) {
  __shared__ unsigned short W1[128 * 128];
  __shared__ unsigned short W2[128 * 128];
  __shared__ unsigned short X[64 * 128];
  const int tid = threadIdx.x;
  const int w = tid >> 6, l = tid & 63, l16 = l & 15, lh = l >> 4;
  const int zi = blockIdx.x >> 7, rb = blockIdx.x & 127;
  const float* zg = (zi ? z2 : z1) + (size_t)rb * 64 * 128;
  unsigned short* outp = (zi ? hs2 : hs1) + (size_t)rb * 64 * 128;

  float bias1[8], bias2[8];
#pragma unroll
  for (int nf = 0; nf < 8; ++nf) {
    bias1[nf] = b1g[nf * 16 + l16];
    bias2[nf] = b2g[nf * 16 + l16];
  }

#pragma unroll
  for (int t = 0; t < 16; ++t) {
    int c = tid + t * 256;
    int r = c >> 5, q = c & 31;
    int off = r * 256 + ((((q >> 1) ^ (r & 7)) << 4) | ((q & 1) << 3));
    f32x4 va = *(const f32x4*)&w1g[c * 4];
    f32x4 vb = *(const f32x4*)&w2g[c * 4];
    uint2 pa, pb;
    pa.x = f2bf(va.x) | (f2bf(va.y) << 16);
    pa.y = f2bf(va.z) | (f2bf(va.w) << 16);
    pb.x = f2bf(vb.x) | (f2bf(vb.y) << 16);
    pb.y = f2bf(vb.z) | (f2bf(vb.w) << 16);
    *(uint2*)((char*)W1 + off) = pa;
    *(uint2*)((char*)W2 + off) = pb;
  }
#pragma unroll
  for (int t = 0; t < 8; ++t) {
    int c = tid + t * 256;
    int r = c >> 5, q = c & 31;
    int off = r * 256 + ((((q >> 1) ^ (r & 7)) << 4) | ((q & 1) << 3));
    f32x4 v = *(const f32x4*)&zg[c * 4];
    uint2 p;
    p.x = f2bf(v.x) | (f2bf(v.y) << 16);
    p.y = f2bf(v.z) | (f2bf(v.w) << 16);
    *(uint2*)((char*)X + off) = p;
  }
  __syncthreads();

  const f32x4 ZERO = {0.f, 0.f, 0.f, 0.f};
  const int arow = w * 16 + l16;

  short8 a1[4];
#pragma unroll
  for (int ks = 0; ks < 4; ++ks)
    a1[ks] = *(const short8*)((const char*)X + arow * 256 +
                              ((ks * 64 + lh * 16) ^ ((arow & 7) << 4)));
  f32x4 h[8];
#pragma unroll
  for (int nf = 0; nf < 8; ++nf) {
    const int brow = nf * 16 + l16;
    const char* bp = (const char*)W1 + brow * 256;
    f32x4 c = ZERO;
#pragma unroll
    for (int ks = 0; ks < 4; ++ks) {
      short8 b = *(const short8*)(bp + ((ks * 64 + lh * 16) ^ ((brow & 7) << 4)));
      c = __builtin_amdgcn_mfma_f32_16x16x32_bf16(a1[ks], b, c, 0, 0, 0);
    }
#pragma unroll
    for (int r = 0; r < 4; ++r) {
      float x = c[r] + bias1[nf];
      c[r] = x > 0.f ? x : expm1f(x);
    }
    h[nf] = c;
  }
  __syncthreads();

#pragma unroll
  for (int nf = 0; nf < 8; ++nf)
#pragma unroll
    for (int r = 0; r < 4; ++r) {
      int row = w * 16 + lh * 4 + r;
      int c2 = (nf * 16 + l16) * 2;
      int off = row * 256 + ((c2 & ~15) ^ ((row & 7) << 4)) + (c2 & 15);
      *(unsigned short*)((char*)X + off) = (unsigned short)f2bf(h[nf][r]);
    }
  __syncthreads();

  short8 a2[4];
#pragma unroll
  for (int ks = 0; ks < 4; ++ks)
    a2[ks] = *(const short8*)((const char*)X + arow * 256 +
                              ((ks * 64 + lh * 16) ^ ((arow & 7) << 4)));
  f32x4 o[8];
#pragma unroll
  for (int nf = 0; nf < 8; ++nf) {
    const int brow = nf * 16 + l16;
    const char* bp = (const char*)W2 + brow * 256;
    f32x4 c = ZERO;
#pragma unroll
    for (int ks = 0; ks < 4; ++ks) {
      short8 b = *(const short8*)(bp + ((ks * 64 + lh * 16) ^ ((brow & 7) << 4)));
      c = __builtin_amdgcn_mfma_f32_16x16x32_bf16(a2[ks], b, c, 0, 0, 0);
    }
#pragma unroll
    for (int r = 0; r < 4; ++r) c[r] += bias2[nf];
    o[nf] = c;
  }

  float ss[4] = {0.f, 0.f, 0.f, 0.f};
#pragma unroll
  for (int nf = 0; nf < 8; ++nf)
#pragma unroll
    for (int r = 0; r < 4; ++r) ss[r] += o[nf][r] * o[nf][r];
#pragma unroll
  for (int m = 1; m <= 8; m <<= 1)
#pragma unroll
    for (int r = 0; r < 4; ++r) ss[r] += __shfl_xor(ss[r], m, 64);
  float sc[4];
#pragma unroll
  for (int r = 0; r < 4; ++r)
    sc[r] = 1.6986436005760381f / fmaxf(sqrtf(ss[r]), 1e-12f);

#pragma unroll
  for (int nf = 0; nf < 8; ++nf)
#pragma unroll
    for (int r = 0; r < 4; ++r) {
      int row = w * 16 + lh * 4 + r;
      int c2 = (nf * 16 + l16) * 2;
      int off = row * 256 + ((c2 & ~15) ^ ((row & 7) << 4)) + (c2 & 15);
      *(unsigned short*)((char*)outp + off) = (unsigned short)f2bf(o[nf][r] * sc[r]);
    }
}

// ---------------------------------------------------------------------------
// Kernel 2: fused Gram + exp2 + row-sum (+ col-sum in pass 2).
// 3 passes: 0 -> R11 (z1 x z1), 1 -> R22 (z2 x z2), 2 -> z1 x z2 giving both
// R12 (row-sums) and R21 (col-sums, per-rowblock partials).
// Grid 768 = 3 passes x 16 rowblocks(512 rows) x 16 col-ranges(512 cols),
// 512 threads (8 waves) x 3 blocks/CU -> 6 waves/SIMD (TLP to hide the
// MFMA-chain + exp2 latency; round-6 had only 2/SIMD -> 75% idle pipes).
// __launch_bounds__(512,6): VGPR cap 341 -> af[4][4] (64 regs) resident,
// no spill (rounds 2/5 lesson: caps of 128 spilled af).
// MFMA order: ks-outer/mf-inner -> dependency distance 4 on each acc chain.
// B tiles 64x128 double-buffered (2x16KB) via global_load_lds DMA.
// ---------------------------------------------------------------------------
__global__ __launch_bounds__(512, 6) void gram_kernel(
    const unsigned short* __restrict__ hs1, const unsigned short* __restrict__ hs2,
    float* __restrict__ Rp,     // [48][8192] (pass*16+cr) row-sum partials
    float* __restrict__ R21p) { // [16][8192] col-sum partials (pass 2)
  __shared__ unsigned short Bbuf[2][64 * 128];
  __shared__ float csbuf[2][8][64];

  const int tid = threadIdx.x;
  const int w = tid >> 6, l = tid & 63, l16 = l & 15, lh = l >> 4;
  const int pass = blockIdx.x >> 8;
  const int idx = blockIdx.x & 255;
  const int rb = idx >> 4;  // 16 rowblocks of 512 rows
  const int cr = idx & 15;  // 16 col-ranges of 512 cols

  const unsigned short* Ag = (pass == 1) ? hs2 : hs1;
  const unsigned short* Bg = (pass == 0) ? hs1 : hs2;
  const char* bbase = (const char*)Bg + (size_t)cr * (512 * 256);
  const bool do_cs = (pass == 2);

  auto STAGE = [&](int buf, int ct) {
#pragma unroll
    for (int s = 0; s < 2; ++s) {
      const char* src = bbase + (size_t)ct * 16384 + s * 8192 + tid * 16;
      char* dst = (char*)Bbuf[buf] + s * 8192 + w * 1024;  // wave-uniform base
      __builtin_amdgcn_global_load_lds(
          (const __attribute__((address_space(1))) void*)src,
          (__attribute__((address_space(3))) void*)dst, 16, 0, 0);
    }
  };

  STAGE(0, 0);

  short8 af[4][4];  // 64 rows per wave, resident (64 VGPRs)
  {
    const char* abase = (const char*)Ag + ((size_t)rb * 512 + w * 64) * 256;
#pragma unroll
    for (int mf = 0; mf < 4; ++mf) {
      int row = mf * 16 + l16;
#pragma unroll
      for (int ks = 0; ks < 4; ++ks)
        af[mf][ks] = *(const short8*)(abase + row * 256 +
                                      ((ks * 64 + lh * 16) ^ ((row & 7) << 4)));
    }
  }

  float rs[4][4];
#pragma unroll
  for (int mf = 0; mf < 4; ++mf)
#pragma unroll
    for (int r = 0; r < 4; ++r) rs[mf][r] = 0.f;
  const f32x4 ZERO = {0.f, 0.f, 0.f, 0.f};

  __syncthreads();  // tile 0 staged

  for (int ct = 0; ct < 8; ++ct) {
    const int cur = ct & 1;
    if (ct + 1 < 8) STAGE(cur ^ 1, ct + 1);
    if (do_cs && w == 0 && ct > 0) {  // flush prev tile's col-sums (overlaps)
      float v = 0.f;
#pragma unroll
      for (int ww = 0; ww < 8; ++ww) v += csbuf[(ct - 1) & 1][ww][l];
      R21p[(size_t)rb * NROWS + cr * 512 + (ct - 1) * 64 + l] = v;
    }
#pragma unroll
    for (int nf = 0; nf < 4; ++nf) {
      short8 bf[4];
      const int brow = nf * 16 + l16;
      const char* bp = (const char*)Bbuf[cur] + brow * 256;
#pragma unroll
      for (int ks = 0; ks < 4; ++ks)
        bf[ks] = *(const short8*)(bp + ((ks * 64 + lh * 16) ^ ((brow & 7) << 4)));
      f32x4 c[4] = {ZERO, ZERO, ZERO, ZERO};
#pragma unroll
      for (int ks = 0; ks < 4; ++ks)  // ks-outer: dep distance 4 per chain
#pragma unroll
        for (int mf = 0; mf < 4; ++mf)
          c[mf] = __builtin_amdgcn_mfma_f32_16x16x32_bf16(af[mf][ks], bf[ks], c[mf], 0, 0, 0);
      float cs = 0.f;
#pragma unroll
      for (int mf = 0; mf < 4; ++mf)
#pragma unroll
        for (int r = 0; r < 4; ++r) {  // pre-scaled: exp2(c) = exp(s/TAU)
          float e = fast_exp2(c[mf][r]);
          rs[mf][r] += e;
          if (do_cs) cs += e;
        }
      if (do_cs) {
        cs += __shfl_xor(cs, 16, 64);
        cs += __shfl_xor(cs, 32, 64);
        if (lh == 0) csbuf[cur][w][nf * 16 + l16] = cs;
      }
    }
    __syncthreads();
  }
  if (do_cs && w == 0) {  // flush last tile (ct=7 -> buf 1)
    float v = 0.f;
#pragma unroll
    for (int ww = 0; ww < 8; ++ww) v += csbuf[1][ww][l];
    R21p[(size_t)rb * NROWS + cr * 512 + 7 * 64 + l] = v;
  }

  // row-sums: reduce over the 16 col-lanes; A-row = mf*16 + lh*4 + r [m89]
#pragma unroll
  for (int m = 1; m <= 8; m <<= 1)
#pragma unroll
    for (int mf = 0; mf < 4; ++mf)
#pragma unroll
      for (int r = 0; r < 4; ++r) rs[mf][r] += __shfl_xor(rs[mf][r], m, 64);
  if (l16 == 0) {
    float* base = &Rp[(size_t)(pass * 16 + cr) * NROWS + rb * 512 + w * 64];
#pragma unroll
    for (int mf = 0; mf < 4; ++mf) {
      f32x4 v = {rs[mf][0], rs[mf][1], rs[mf][2], rs[mf][3]};
      *(f32x4*)(base + mf * 16 + lh * 4) = v;
    }
  }
}

// ---------------------------------------------------------------------------
// Kernel 3: per-row denominators (coalesced partial reduction).
// ---------------------------------------------------------------------------
__global__ __launch_bounds__(256) void denom_kernel(
    const float* __restrict__ Rp, const float* __restrict__ R21p,
    float* __restrict__ dlog) {
  const int i = blockIdx.x * 256 + threadIdx.x;
  const float E2 = 7.3890560989306495f;
  float r11 = 0.f, r22 = 0.f, r12 = 0.f, r21 = 0.f;
#pragma unroll
  for (int k = 0; k < 16; ++k) r11 += Rp[(size_t)k * NROWS + i];
#pragma unroll
  for (int k = 16; k < 32; ++k) r22 += Rp[(size_t)k * NROWS + i];
#pragma unroll
  for (int k = 32; k < 48; ++k) r12 += Rp[(size_t)k * NROWS + i];
#pragma unroll
  for (int rb = 0; rb < 16; ++rb) r21 += R21p[(size_t)rb * NROWS + i];
  dlog[i] = 0.5f * (logf(r11 + r12 - E2) + logf(r22 + r21 - E2));
}

// ---------------------------------------------------------------------------
// Kernel 4: diag dots + per-row loss + block partials (deterministic).
// loss_i = -ln2 * dot_i + dlog[i]   (dot of alpha-scaled rows = 2*log2(e)*s)
// ---------------------------------------------------------------------------
__global__ __launch_bounds__(256) void loss_kernel(
    const unsigned short* __restrict__ hs1, const unsigned short* __restrict__ hs2,
    const float* __restrict__ dlog, float* __restrict__ partial) {
  const int tid = threadIdx.x;
  const int l = tid & 63;
  const int wv = tid >> 6;
  const int gw = blockIdx.x * 4 + wv;  // 0..1023
  const float LN2 = 0.6931471805599453f;
  float acc = 0.f;
  for (int t = 0; t < 8; ++t) {
    int i = gw * 8 + t;
    int off = (((l << 2) & ~15) ^ ((i & 7) << 4)) | ((l & 3) << 2);
    unsigned int a = *(const unsigned int*)((const char*)hs1 + (size_t)i * 256 + off);
    unsigned int b = *(const unsigned int*)((const char*)hs2 + (size_t)i * 256 + off);
    float p = bf2f(a & 0xffffu) * bf2f(b & 0xffffu) + bf2f(a >> 16) * bf2f(b >> 16);
#pragma unroll
    for (int m = 1; m < 64; m <<= 1) p += __shfl_xor(p, m, 64);
    if (l == 0) acc += -LN2 * p + dlog[i];
  }
  __shared__ float wacc[4];
  if (l == 0) wacc[wv] = acc;
  __syncthreads();
  if (tid == 0) partial[blockIdx.x] = wacc[0] + wacc[1] + wacc[2] + wacc[3];
}

__global__ void loss_final(const float* __restrict__ partial, float* __restrict__ outp) {
  const int t = threadIdx.x;
  float v = partial[t] + partial[t + 64] + partial[t + 128] + partial[t + 192];
#pragma unroll
  for (int m = 1; m < 64; m <<= 1) v += __shfl_xor(v, m, 64);
  if (t == 0) outp[0] = v * (1.0f / 8192.0f);
}

// ---------------------------------------------------------------------------
extern "C" void kernel_launch(void* const* d_in, const int* in_sizes, int n_in,
                              void* d_out, int out_size, void* d_ws, size_t ws_size,
                              hipStream_t stream) {
  const float* z1 = (const float*)d_in[0];
  const float* z2 = (const float*)d_in[1];
  const float* w1 = (const float*)d_in[2];
  const float* b1 = (const float*)d_in[3];
  const float* w2 = (const float*)d_in[4];
  const float* b2 = (const float*)d_in[5];
  char* ws = (char*)d_ws;
  unsigned short* hs1 = (unsigned short*)ws;                              // 2 MB
  unsigned short* hs2 = (unsigned short*)(ws + (size_t)2 * 1024 * 1024);  // 2 MB
  float* Rp = (float*)(ws + (size_t)4 * 1024 * 1024);                     // 48*8192*4 = 1.5 MB
  float* R21p = (float*)(ws + (size_t)4 * 1024 * 1024 + 1536 * 1024);     // 16*8192*4 = 512 KB
  float* dlog = (float*)(ws + (size_t)6 * 1024 * 1024);                   // 32 KB
  float* partial = (float*)(ws + (size_t)6 * 1024 * 1024 + 64 * 1024);    // 1 KB
  float* outp = (float*)d_out;

  proj_kernel<<<dim3(256), dim3(256), 0, stream>>>(z1, z2, w1, b1, w2, b2, hs1, hs2);
  gram_kernel<<<dim3(768), dim3(512), 0, stream>>>(hs1, hs2, Rp, R21p);
  denom_kernel<<<dim3(32), dim3(256), 0, stream>>>(Rp, R21p, dlog);
  loss_kernel<<<dim3(256), dim3(256), 0, stream>>>(hs1, hs2, dlog, partial);
  loss_final<<<dim3(1), dim3(64), 0, stream>>>(partial, outp);
}

// Round 8
// 102.338 us; speedup vs baseline: 4.9214x; 4.9214x over previous
//
#include <hip/hip_runtime.h>
#include <stdint.h>

typedef __attribute__((ext_vector_type(4))) float f32x4;
typedef __attribute__((ext_vector_type(8))) short short8;

#define NROWS 8192

static __device__ __forceinline__ unsigned int f2bf(float f) {
  unsigned int u = __float_as_uint(f);
  return (u + 0x7fffu + ((u >> 16) & 1u)) >> 16;  // RNE
}
static __device__ __forceinline__ float bf2f(unsigned int h) {
  return __uint_as_float(h << 16);
}
static __device__ __forceinline__ float fast_exp2(float x) {
  // args bounded (|x| < 3): raw v_exp_f32, skip OCML range/denorm handling
#if __has_builtin(__builtin_amdgcn_exp2f)
  return __builtin_amdgcn_exp2f(x);
#else
  float r;
  asm("v_exp_f32 %0, %1" : "=v"(r) : "v"(x));
  return r;
#endif
}

// hs layout: per 256B row r, 16B chunk c stored at chunk position c ^ (r&7).
// Linear global->LDS DMA then yields the bank-conflict-free swizzled LDS
// layout for ds_read_b128 fragments (G4 / m201 pre-swizzled-source pattern).

// ---------------------------------------------------------------------------
// Kernel 1: projection fc2(elu(fc1(z))) + L2-normalize, bf16 MFMA + f32
// epilogue. 256 blocks x 256 threads; block = 64 rows of one z. Output rows
// pre-scaled by sqrt(2*log2 e) so Gram MFMA output is the exp2 argument,
// written in the swizzled global layout.
// ---------------------------------------------------------------------------
__global__ __launch_bounds__(256) void proj_kernel(
    const float* __restrict__ z1, const float* __restrict__ z2,
    const float* __restrict__ w1g, const float* __restrict__ b1g,
    const float* __restrict__ w2g, const float* __restrict__ b2g,
    unsigned short* __restrict__ hs1, unsigned short* __restrict__ hs2) {
  __shared__ unsigned short W1[128 * 128];
  __shared__ unsigned short W2[128 * 128];
  __shared__ unsigned short X[64 * 128];
  const int tid = threadIdx.x;
  const int w = tid >> 6, l = tid & 63, l16 = l & 15, lh = l >> 4;
  const int zi = blockIdx.x >> 7, rb = blockIdx.x & 127;
  const float* zg = (zi ? z2 : z1) + (size_t)rb * 64 * 128;
  unsigned short* outp = (zi ? hs2 : hs1) + (size_t)rb * 64 * 128;

  float bias1[8], bias2[8];
#pragma unroll
  for (int nf = 0; nf < 8; ++nf) {
    bias1[nf] = b1g[nf * 16 + l16];
    bias2[nf] = b2g[nf * 16 + l16];
  }

#pragma unroll
  for (int t = 0; t < 16; ++t) {
    int c = tid + t * 256;
    int r = c >> 5, q = c & 31;
    int off = r * 256 + ((((q >> 1) ^ (r & 7)) << 4) | ((q & 1) << 3));
    f32x4 va = *(const f32x4*)&w1g[c * 4];
    f32x4 vb = *(const f32x4*)&w2g[c * 4];
    uint2 pa, pb;
    pa.x = f2bf(va.x) | (f2bf(va.y) << 16);
    pa.y = f2bf(va.z) | (f2bf(va.w) << 16);
    pb.x = f2bf(vb.x) | (f2bf(vb.y) << 16);
    pb.y = f2bf(vb.z) | (f2bf(vb.w) << 16);
    *(uint2*)((char*)W1 + off) = pa;
    *(uint2*)((char*)W2 + off) = pb;
  }
#pragma unroll
  for (int t = 0; t < 8; ++t) {
    int c = tid + t * 256;
    int r = c >> 5, q = c & 31;
    int off = r * 256 + ((((q >> 1) ^ (r & 7)) << 4) | ((q & 1) << 3));
    f32x4 v = *(const f32x4*)&zg[c * 4];
    uint2 p;
    p.x = f2bf(v.x) | (f2bf(v.y) << 16);
    p.y = f2bf(v.z) | (f2bf(v.w) << 16);
    *(uint2*)((char*)X + off) = p;
  }
  __syncthreads();

  const f32x4 ZERO = {0.f, 0.f, 0.f, 0.f};
  const int arow = w * 16 + l16;

  short8 a1[4];
#pragma unroll
  for (int ks = 0; ks < 4; ++ks)
    a1[ks] = *(const short8*)((const char*)X + arow * 256 +
                              ((ks * 64 + lh * 16) ^ ((arow & 7) << 4)));
  f32x4 h[8];
#pragma unroll
  for (int nf = 0; nf < 8; ++nf) {
    const int brow = nf * 16 + l16;
    const char* bp = (const char*)W1 + brow * 256;
    f32x4 c = ZERO;
#pragma unroll
    for (int ks = 0; ks < 4; ++ks) {
      short8 b = *(const short8*)(bp + ((ks * 64 + lh * 16) ^ ((brow & 7) << 4)));
      c = __builtin_amdgcn_mfma_f32_16x16x32_bf16(a1[ks], b, c, 0, 0, 0);
    }
#pragma unroll
    for (int r = 0; r < 4; ++r) {
      float x = c[r] + bias1[nf];
      c[r] = x > 0.f ? x : expm1f(x);
    }
    h[nf] = c;
  }
  __syncthreads();

#pragma unroll
  for (int nf = 0; nf < 8; ++nf)
#pragma unroll
    for (int r = 0; r < 4; ++r) {
      int row = w * 16 + lh * 4 + r;
      int c2 = (nf * 16 + l16) * 2;
      int off = row * 256 + ((c2 & ~15) ^ ((row & 7) << 4)) + (c2 & 15);
      *(unsigned short*)((char*)X + off) = (unsigned short)f2bf(h[nf][r]);
    }
  __syncthreads();

  short8 a2[4];
#pragma unroll
  for (int ks = 0; ks < 4; ++ks)
    a2[ks] = *(const short8*)((const char*)X + arow * 256 +
                              ((ks * 64 + lh * 16) ^ ((arow & 7) << 4)));
  f32x4 o[8];
#pragma unroll
  for (int nf = 0; nf < 8; ++nf) {
    const int brow = nf * 16 + l16;
    const char* bp = (const char*)W2 + brow * 256;
    f32x4 c = ZERO;
#pragma unroll
    for (int ks = 0; ks < 4; ++ks) {
      short8 b = *(const short8*)(bp + ((ks * 64 + lh * 16) ^ ((brow & 7) << 4)));
      c = __builtin_amdgcn_mfma_f32_16x16x32_bf16(a2[ks], b, c, 0, 0, 0);
    }
#pragma unroll
    for (int r = 0; r < 4; ++r) c[r] += bias2[nf];
    o[nf] = c;
  }

  float ss[4] = {0.f, 0.f, 0.f, 0.f};
#pragma unroll
  for (int nf = 0; nf < 8; ++nf)
#pragma unroll
    for (int r = 0; r < 4; ++r) ss[r] += o[nf][r] * o[nf][r];
#pragma unroll
  for (int m = 1; m <= 8; m <<= 1)
#pragma unroll
    for (int r = 0; r < 4; ++r) ss[r] += __shfl_xor(ss[r], m, 64);
  float sc[4];
#pragma unroll
  for (int r = 0; r < 4; ++r)
    sc[r] = 1.6986436005760381f / fmaxf(sqrtf(ss[r]), 1e-12f);

#pragma unroll
  for (int nf = 0; nf < 8; ++nf)
#pragma unroll
    for (int r = 0; r < 4; ++r) {
      int row = w * 16 + lh * 4 + r;
      int c2 = (nf * 16 + l16) * 2;
      int off = row * 256 + ((c2 & ~15) ^ ((row & 7) << 4)) + (c2 & 15);
      *(unsigned short*)((char*)outp + off) = (unsigned short)f2bf(o[nf][r] * sc[r]);
    }
}

// ---------------------------------------------------------------------------
// Kernel 2: fused Gram + exp2 + row-sum (+ col-sum in pass 2).
// 3 passes: 0 -> R11 (z1 x z1), 1 -> R22 (z2 x z2), 2 -> z1 x z2 giving both
// R12 (row-sums) and R21 (col-sums, per-rowblock partials).
// Grid 768 = 3 passes x 32 rowblocks(256 rows) x 8 col-ranges(1024 cols),
// 256 threads (4 waves, 1 wave/SIMD) -> 3 blocks/CU, 3 waves/SIMD.
// __launch_bounds__(256,3): VGPR cap 170 (per-SIMD file = 512/lane) so
// af[4][4] (64 VGPR) stays resident WITHOUT spill. Round-7 lesson: (512,6)
// caps at 512/6=85 -> total spill, 1.9GB scratch traffic. DO NOT raise waves.
// MFMA order ks-outer/mf-inner: dep distance 4 per acc chain (round-6 was
// mf-outer = serial chains -> latency-bound at 25% MfmaUtil).
// B tiles 64x128 double-buffered (2x16KB) via global_load_lds DMA.
// ---------------------------------------------------------------------------
__global__ __launch_bounds__(256, 3) void gram_kernel(
    const unsigned short* __restrict__ hs1, const unsigned short* __restrict__ hs2,
    float* __restrict__ Rp,     // [24][8192] (pass*8+cr) row-sum partials
    float* __restrict__ R21p) { // [32][8192] col-sum partials (pass 2)
  __shared__ unsigned short Bbuf[2][64 * 128];
  __shared__ float csbuf[2][4][64];

  const int tid = threadIdx.x;
  const int w = tid >> 6, l = tid & 63, l16 = l & 15, lh = l >> 4;
  const int pass = blockIdx.x >> 8;
  const int idx = blockIdx.x & 255;
  const int rb = idx >> 3;  // 32 rowblocks of 256 rows
  const int cr = idx & 7;   // 8 col-ranges of 1024 cols

  const unsigned short* Ag = (pass == 1) ? hs2 : hs1;
  const unsigned short* Bg = (pass == 0) ? hs1 : hs2;
  const char* bbase = (const char*)Bg + (size_t)cr * (1024 * 256);
  const bool do_cs = (pass == 2);

  auto STAGE = [&](int buf, int ct) {
#pragma unroll
    for (int s = 0; s < 4; ++s) {
      const char* src = bbase + (size_t)ct * 16384 + s * 4096 + tid * 16;
      char* dst = (char*)Bbuf[buf] + s * 4096 + w * 1024;  // wave-uniform base
      __builtin_amdgcn_global_load_lds(
          (const __attribute__((address_space(1))) void*)src,
          (__attribute__((address_space(3))) void*)dst, 16, 0, 0);
    }
  };

  STAGE(0, 0);

  short8 af[4][4];  // 64 rows per wave, resident (64 VGPRs)
  {
    const char* abase = (const char*)Ag + ((size_t)rb * 256 + w * 64) * 256;
#pragma unroll
    for (int mf = 0; mf < 4; ++mf) {
      int row = mf * 16 + l16;
#pragma unroll
      for (int ks = 0; ks < 4; ++ks)
        af[mf][ks] = *(const short8*)(abase + row * 256 +
                                      ((ks * 64 + lh * 16) ^ ((row & 7) << 4)));
    }
  }

  float rs[4][4];
#pragma unroll
  for (int mf = 0; mf < 4; ++mf)
#pragma unroll
    for (int r = 0; r < 4; ++r) rs[mf][r] = 0.f;
  const f32x4 ZERO = {0.f, 0.f, 0.f, 0.f};

  __syncthreads();  // tile 0 staged

  for (int ct = 0; ct < 16; ++ct) {
    const int cur = ct & 1;
    if (ct + 1 < 16) STAGE(cur ^ 1, ct + 1);
    if (do_cs && w == 0 && ct > 0) {  // flush prev tile's col-sums (overlaps)
      float v = (csbuf[cur ^ 1][0][l] + csbuf[cur ^ 1][1][l]) +
                (csbuf[cur ^ 1][2][l] + csbuf[cur ^ 1][3][l]);
      R21p[(size_t)rb * NROWS + cr * 1024 + (ct - 1) * 64 + l] = v;
    }
#pragma unroll
    for (int nf = 0; nf < 4; ++nf) {
      short8 bf[4];
      const int brow = nf * 16 + l16;
      const char* bp = (const char*)Bbuf[cur] + brow * 256;
#pragma unroll
      for (int ks = 0; ks < 4; ++ks)
        bf[ks] = *(const short8*)(bp + ((ks * 64 + lh * 16) ^ ((brow & 7) << 4)));
      f32x4 c[4] = {ZERO, ZERO, ZERO, ZERO};
#pragma unroll
      for (int ks = 0; ks < 4; ++ks)  // ks-outer: dep distance 4 per chain
#pragma unroll
        for (int mf = 0; mf < 4; ++mf)
          c[mf] = __builtin_amdgcn_mfma_f32_16x16x32_bf16(af[mf][ks], bf[ks], c[mf], 0, 0, 0);
      float cs = 0.f;
#pragma unroll
      for (int mf = 0; mf < 4; ++mf)
#pragma unroll
        for (int r = 0; r < 4; ++r) {  // pre-scaled: exp2(c) = exp(s/TAU)
          float e = fast_exp2(c[mf][r]);
          rs[mf][r] += e;
          if (do_cs) cs += e;
        }
      if (do_cs) {
        cs += __shfl_xor(cs, 16, 64);
        cs += __shfl_xor(cs, 32, 64);
        if (lh == 0) csbuf[cur][w][nf * 16 + l16] = cs;
      }
    }
    __syncthreads();
  }
  if (do_cs && w == 0) {  // flush last tile (ct=15 -> buf 1)
    float v = (csbuf[1][0][l] + csbuf[1][1][l]) + (csbuf[1][2][l] + csbuf[1][3][l]);
    R21p[(size_t)rb * NROWS + cr * 1024 + 15 * 64 + l] = v;
  }

  // row-sums: reduce over the 16 col-lanes; A-row = mf*16 + lh*4 + r [m89]
#pragma unroll
  for (int m = 1; m <= 8; m <<= 1)
#pragma unroll
    for (int mf = 0; mf < 4; ++mf)
#pragma unroll
      for (int r = 0; r < 4; ++r) rs[mf][r] += __shfl_xor(rs[mf][r], m, 64);
  if (l16 == 0) {
    float* base = &Rp[(size_t)(pass * 8 + cr) * NROWS + rb * 256 + w * 64];
#pragma unroll
    for (int mf = 0; mf < 4; ++mf) {
      f32x4 v = {rs[mf][0], rs[mf][1], rs[mf][2], rs[mf][3]};
      *(f32x4*)(base + mf * 16 + lh * 4) = v;
    }
  }
}

// ---------------------------------------------------------------------------
// Kernel 3: per-row denominators (coalesced partial reduction).
// ---------------------------------------------------------------------------
__global__ __launch_bounds__(256) void denom_kernel(
    const float* __restrict__ Rp, const float* __restrict__ R21p,
    float* __restrict__ dlog) {
  const int i = blockIdx.x * 256 + threadIdx.x;
  const float E2 = 7.3890560989306495f;
  float r11 = 0.f, r22 = 0.f, r12 = 0.f, r21 = 0.f;
#pragma unroll
  for (int k = 0; k < 8; ++k) r11 += Rp[(size_t)k * NROWS + i];
#pragma unroll
  for (int k = 8; k < 16; ++k) r22 += Rp[(size_t)k * NROWS + i];
#pragma unroll
  for (int k = 16; k < 24; ++k) r12 += Rp[(size_t)k * NROWS + i];
#pragma unroll
  for (int rb = 0; rb < 32; ++rb) r21 += R21p[(size_t)rb * NROWS + i];
  dlog[i] = 0.5f * (logf(r11 + r12 - E2) + logf(r22 + r21 - E2));
}

// ---------------------------------------------------------------------------
// Kernel 4: diag dots + per-row loss + block partials (deterministic).
// loss_i = -ln2 * dot_i + dlog[i]   (dot of alpha-scaled rows = 2*log2(e)*s)
// ---------------------------------------------------------------------------
__global__ __launch_bounds__(256) void loss_kernel(
    const unsigned short* __restrict__ hs1, const unsigned short* __restrict__ hs2,
    const float* __restrict__ dlog, float* __restrict__ partial) {
  const int tid = threadIdx.x;
  const int l = tid & 63;
  const int wv = tid >> 6;
  const int gw = blockIdx.x * 4 + wv;  // 0..1023
  const float LN2 = 0.6931471805599453f;
  float acc = 0.f;
  for (int t = 0; t < 8; ++t) {
    int i = gw * 8 + t;
    int off = (((l << 2) & ~15) ^ ((i & 7) << 4)) | ((l & 3) << 2);
    unsigned int a = *(const unsigned int*)((const char*)hs1 + (size_t)i * 256 + off);
    unsigned int b = *(const unsigned int*)((const char*)hs2 + (size_t)i * 256 + off);
    float p = bf2f(a & 0xffffu) * bf2f(b & 0xffffu) + bf2f(a >> 16) * bf2f(b >> 16);
#pragma unroll
    for (int m = 1; m < 64; m <<= 1) p += __shfl_xor(p, m, 64);
    if (l == 0) acc += -LN2 * p + dlog[i];
  }
  __shared__ float wacc[4];
  if (l == 0) wacc[wv] = acc;
  __syncthreads();
  if (tid == 0) partial[blockIdx.x] = wacc[0] + wacc[1] + wacc[2] + wacc[3];
}

__global__ void loss_final(const float* __restrict__ partial, float* __restrict__ outp) {
  const int t = threadIdx.x;
  float v = partial[t] + partial[t + 64] + partial[t + 128] + partial[t + 192];
#pragma unroll
  for (int m = 1; m < 64; m <<= 1) v += __shfl_xor(v, m, 64);
  if (t == 0) outp[0] = v * (1.0f / 8192.0f);
}

// ---------------------------------------------------------------------------
extern "C" void kernel_launch(void* const* d_in, const int* in_sizes, int n_in,
                              void* d_out, int out_size, void* d_ws, size_t ws_size,
                              hipStream_t stream) {
  const float* z1 = (const float*)d_in[0];
  const float* z2 = (const float*)d_in[1];
  const float* w1 = (const float*)d_in[2];
  const float* b1 = (const float*)d_in[3];
  const float* w2 = (const float*)d_in[4];
  const float* b2 = (const float*)d_in[5];
  char* ws = (char*)d_ws;
  unsigned short* hs1 = (unsigned short*)ws;                              // 2 MB
  unsigned short* hs2 = (unsigned short*)(ws + (size_t)2 * 1024 * 1024);  // 2 MB
  float* Rp = (float*)(ws + (size_t)4 * 1024 * 1024);                     // 24*8192*4 = 768 KB
  float* R21p = (float*)(ws + (size_t)4 * 1024 * 1024 + 768 * 1024);      // 32*8192*4 = 1 MB
  float* dlog = (float*)(ws + (size_t)6 * 1024 * 1024);                   // 32 KB
  float* partial = (float*)(ws + (size_t)6 * 1024 * 1024 + 64 * 1024);    // 1 KB
  float* outp = (float*)d_out;

  proj_kernel<<<dim3(256), dim3(256), 0, stream>>>(z1, z2, w1, b1, w2, b2, hs1, hs2);
  gram_kernel<<<dim3(768), dim3(256), 0, stream>>>(hs1, hs2, Rp, R21p);
  denom_kernel<<<dim3(32), dim3(256), 0, stream>>>(Rp, R21p, dlog);
  loss_kernel<<<dim3(256), dim3(256), 0, stream>>>(hs1, hs2, dlog, partial);
  loss_final<<<dim3(1), dim3(64), 0, stream>>>(partial, outp);
}

// Round 9
// 88.802 us; speedup vs baseline: 5.6716x; 1.1524x over previous
//
#include <hip/hip_runtime.h>
#include <stdint.h>

typedef __attribute__((ext_vector_type(4))) float f32x4;
typedef __attribute__((ext_vector_type(8))) short short8;

#define NROWS 8192

static __device__ __forceinline__ unsigned int f2bf(float f) {
  unsigned int u = __float_as_uint(f);
  return (u + 0x7fffu + ((u >> 16) & 1u)) >> 16;  // RNE
}
static __device__ __forceinline__ float bf2f(unsigned int h) {
  return __uint_as_float(h << 16);
}
static __device__ __forceinline__ float fast_exp2(float x) {
  // args bounded (|x| < 3): raw v_exp_f32, skip OCML range/denorm handling
#if __has_builtin(__builtin_amdgcn_exp2f)
  return __builtin_amdgcn_exp2f(x);
#else
  float r;
  asm("v_exp_f32 %0, %1" : "=v"(r) : "v"(x));
  return r;
#endif
}

// hs layout: per 256B row r, 16B chunk c stored at chunk position c ^ (r&7).
// Linear global->LDS DMA then yields the bank-conflict-free swizzled LDS
// layout for ds_read_b128 fragments (G4 / m201 pre-swizzled-source pattern).

// ---------------------------------------------------------------------------
// Kernel 1: projection fc2(elu(fc1(z))) + L2-normalize, bf16 MFMA + f32
// epilogue. 256 blocks x 256 threads; block = 64 rows of one z. Output rows
// pre-scaled by sqrt(2*log2 e) so Gram MFMA output is the exp2 argument,
// written in the swizzled global layout.
// ---------------------------------------------------------------------------
__global__ __launch_bounds__(256) void proj_kernel(
    const float* __restrict__ z1, const float* __restrict__ z2,
    const float* __restrict__ w1g, const float* __restrict__ b1g,
    const float* __restrict__ w2g, const float* __restrict__ b2g,
    unsigned short* __restrict__ hs1, unsigned short* __restrict__ hs2) {
  __shared__ unsigned short W1[128 * 128];
  __shared__ unsigned short W2[128 * 128];
  __shared__ unsigned short X[64 * 128];
  const int tid = threadIdx.x;
  const int w = tid >> 6, l = tid & 63, l16 = l & 15, lh = l >> 4;
  const int zi = blockIdx.x >> 7, rb = blockIdx.x & 127;
  const float* zg = (zi ? z2 : z1) + (size_t)rb * 64 * 128;
  unsigned short* outp = (zi ? hs2 : hs1) + (size_t)rb * 64 * 128;

  float bias1[8], bias2[8];
#pragma unroll
  for (int nf = 0; nf < 8; ++nf) {
    bias1[nf] = b1g[nf * 16 + l16];
    bias2[nf] = b2g[nf * 16 + l16];
  }

#pragma unroll
  for (int t = 0; t < 16; ++t) {
    int c = tid + t * 256;
    int r = c >> 5, q = c & 31;
    int off = r * 256 + ((((q >> 1) ^ (r & 7)) << 4) | ((q & 1) << 3));
    f32x4 va = *(const f32x4*)&w1g[c * 4];
    f32x4 vb = *(const f32x4*)&w2g[c * 4];
    uint2 pa, pb;
    pa.x = f2bf(va.x) | (f2bf(va.y) << 16);
    pa.y = f2bf(va.z) | (f2bf(va.w) << 16);
    pb.x = f2bf(vb.x) | (f2bf(vb.y) << 16);
    pb.y = f2bf(vb.z) | (f2bf(vb.w) << 16);
    *(uint2*)((char*)W1 + off) = pa;
    *(uint2*)((char*)W2 + off) = pb;
  }
#pragma unroll
  for (int t = 0; t < 8; ++t) {
    int c = tid + t * 256;
    int r = c >> 5, q = c & 31;
    int off = r * 256 + ((((q >> 1) ^ (r & 7)) << 4) | ((q & 1) << 3));
    f32x4 v = *(const f32x4*)&zg[c * 4];
    uint2 p;
    p.x = f2bf(v.x) | (f2bf(v.y) << 16);
    p.y = f2bf(v.z) | (f2bf(v.w) << 16);
    *(uint2*)((char*)X + off) = p;
  }
  __syncthreads();

  const f32x4 ZERO = {0.f, 0.f, 0.f, 0.f};
  const int arow = w * 16 + l16;

  short8 a1[4];
#pragma unroll
  for (int ks = 0; ks < 4; ++ks)
    a1[ks] = *(const short8*)((const char*)X + arow * 256 +
                              ((ks * 64 + lh * 16) ^ ((arow & 7) << 4)));
  f32x4 h[8];
#pragma unroll
  for (int nf = 0; nf < 8; ++nf) {
    const int brow = nf * 16 + l16;
    const char* bp = (const char*)W1 + brow * 256;
    f32x4 c = ZERO;
#pragma unroll
    for (int ks = 0; ks < 4; ++ks) {
      short8 b = *(const short8*)(bp + ((ks * 64 + lh * 16) ^ ((brow & 7) << 4)));
      c = __builtin_amdgcn_mfma_f32_16x16x32_bf16(a1[ks], b, c, 0, 0, 0);
    }
#pragma unroll
    for (int r = 0; r < 4; ++r) {
      float x = c[r] + bias1[nf];
      c[r] = x > 0.f ? x : expm1f(x);
    }
    h[nf] = c;
  }
  __syncthreads();

#pragma unroll
  for (int nf = 0; nf < 8; ++nf)
#pragma unroll
    for (int r = 0; r < 4; ++r) {
      int row = w * 16 + lh * 4 + r;
      int c2 = (nf * 16 + l16) * 2;
      int off = row * 256 + ((c2 & ~15) ^ ((row & 7) << 4)) + (c2 & 15);
      *(unsigned short*)((char*)X + off) = (unsigned short)f2bf(h[nf][r]);
    }
  __syncthreads();

  short8 a2[4];
#pragma unroll
  for (int ks = 0; ks < 4; ++ks)
    a2[ks] = *(const short8*)((const char*)X + arow * 256 +
                              ((ks * 64 + lh * 16) ^ ((arow & 7) << 4)));
  f32x4 o[8];
#pragma unroll
  for (int nf = 0; nf < 8; ++nf) {
    const int brow = nf * 16 + l16;
    const char* bp = (const char*)W2 + brow * 256;
    f32x4 c = ZERO;
#pragma unroll
    for (int ks = 0; ks < 4; ++ks) {
      short8 b = *(const short8*)(bp + ((ks * 64 + lh * 16) ^ ((brow & 7) << 4)));
      c = __builtin_amdgcn_mfma_f32_16x16x32_bf16(a2[ks], b, c, 0, 0, 0);
    }
#pragma unroll
    for (int r = 0; r < 4; ++r) c[r] += bias2[nf];
    o[nf] = c;
  }

  float ss[4] = {0.f, 0.f, 0.f, 0.f};
#pragma unroll
  for (int nf = 0; nf < 8; ++nf)
#pragma unroll
    for (int r = 0; r < 4; ++r) ss[r] += o[nf][r] * o[nf][r];
#pragma unroll
  for (int m = 1; m <= 8; m <<= 1)
#pragma unroll
    for (int r = 0; r < 4; ++r) ss[r] += __shfl_xor(ss[r], m, 64);
  float sc[4];
#pragma unroll
  for (int r = 0; r < 4; ++r)
    sc[r] = 1.6986436005760381f / fmaxf(sqrtf(ss[r]), 1e-12f);

#pragma unroll
  for (int nf = 0; nf < 8; ++nf)
#pragma unroll
    for (int r = 0; r < 4; ++r) {
      int row = w * 16 + lh * 4 + r;
      int c2 = (nf * 16 + l16) * 2;
      int off = row * 256 + ((c2 & ~15) ^ ((row & 7) << 4)) + (c2 & 15);
      *(unsigned short*)((char*)outp + off) = (unsigned short)f2bf(o[nf][r] * sc[r]);
    }
}

// ---------------------------------------------------------------------------
// Kernel 2: fused Gram + exp2 + row-sum (+ col-sum in pass 2).
// 3 passes: 0 -> R11, 1 -> R22, 2 -> z1 x z2 (R12 row-sums + R21 col-sums).
// Grid 768 = 3 passes x 32 rowblocks(256) x 8 col-ranges(1024), 256 threads
// (4 waves, 3 blocks/CU = 3 waves/SIMD). __launch_bounds__(256,3): cap 170,
// af[4][4] resident (rounds 2/5/7 lesson: any cap <=128 spills af).
// ROUND-9 CHANGE: deferred-exp pipeline — group nf's exp/rowsum executes
// AFTER group nf+1's MFMAs are issued (cbuf[2] double-buffer, statically
// indexed under full unroll). Removes the ~100cyc MFMA->exp dep-stall that
// blocked in-order issue 4x per iter (r8 showed reordering MFMAs alone = 0).
// Plus T5 setprio(1) around MFMA clusters (independent blocks => attn-like).
// ---------------------------------------------------------------------------
#define EXPBLOCK(G, SLOT)                                             \
  {                                                                   \
    float cs = 0.f;                                                   \
    _Pragma("unroll") for (int mf = 0; mf < 4; ++mf)                  \
        _Pragma("unroll") for (int r = 0; r < 4; ++r) {               \
      float e = fast_exp2(cbuf[SLOT][mf][r]);                         \
      rs[mf][r] += e;                                                 \
      if (do_cs) cs += e;                                             \
    }                                                                 \
    if (do_cs) {                                                      \
      cs += __shfl_xor(cs, 16, 64);                                   \
      cs += __shfl_xor(cs, 32, 64);                                   \
      if (lh == 0) csbuf[cur][w][(G)*16 + l16] = cs;                  \
    }                                                                 \
  }

__global__ __launch_bounds__(256, 3) void gram_kernel(
    const unsigned short* __restrict__ hs1, const unsigned short* __restrict__ hs2,
    float* __restrict__ Rp,     // [24][8192] (pass*8+cr) row-sum partials
    float* __restrict__ R21p) { // [32][8192] col-sum partials (pass 2)
  __shared__ unsigned short Bbuf[2][64 * 128];
  __shared__ float csbuf[2][4][64];

  const int tid = threadIdx.x;
  const int w = tid >> 6, l = tid & 63, l16 = l & 15, lh = l >> 4;
  const int pass = blockIdx.x >> 8;
  const int idx = blockIdx.x & 255;
  const int rb = idx >> 3;  // 32 rowblocks of 256 rows
  const int cr = idx & 7;   // 8 col-ranges of 1024 cols

  const unsigned short* Ag = (pass == 1) ? hs2 : hs1;
  const unsigned short* Bg = (pass == 0) ? hs1 : hs2;
  const char* bbase = (const char*)Bg + (size_t)cr * (1024 * 256);
  const bool do_cs = (pass == 2);

  auto STAGE = [&](int buf, int ct) {
#pragma unroll
    for (int s = 0; s < 4; ++s) {
      const char* src = bbase + (size_t)ct * 16384 + s * 4096 + tid * 16;
      char* dst = (char*)Bbuf[buf] + s * 4096 + w * 1024;  // wave-uniform base
      __builtin_amdgcn_global_load_lds(
          (const __attribute__((address_space(1))) void*)src,
          (__attribute__((address_space(3))) void*)dst, 16, 0, 0);
    }
  };

  STAGE(0, 0);

  short8 af[4][4];  // 64 rows per wave, resident (64 VGPRs)
  {
    const char* abase = (const char*)Ag + ((size_t)rb * 256 + w * 64) * 256;
#pragma unroll
    for (int mf = 0; mf < 4; ++mf) {
      int row = mf * 16 + l16;
#pragma unroll
      for (int ks = 0; ks < 4; ++ks)
        af[mf][ks] = *(const short8*)(abase + row * 256 +
                                      ((ks * 64 + lh * 16) ^ ((row & 7) << 4)));
    }
  }

  float rs[4][4];
#pragma unroll
  for (int mf = 0; mf < 4; ++mf)
#pragma unroll
    for (int r = 0; r < 4; ++r) rs[mf][r] = 0.f;
  const f32x4 ZERO = {0.f, 0.f, 0.f, 0.f};

  __syncthreads();  // tile 0 staged

  for (int ct = 0; ct < 16; ++ct) {
    const int cur = ct & 1;
    if (ct + 1 < 16) STAGE(cur ^ 1, ct + 1);
    if (do_cs && w == 0 && ct > 0) {  // flush prev tile's col-sums (overlaps)
      float v = (csbuf[cur ^ 1][0][l] + csbuf[cur ^ 1][1][l]) +
                (csbuf[cur ^ 1][2][l] + csbuf[cur ^ 1][3][l]);
      R21p[(size_t)rb * NROWS + cr * 1024 + (ct - 1) * 64 + l] = v;
    }
    f32x4 cbuf[2][4];
#pragma unroll
    for (int nf = 0; nf < 4; ++nf) {
      short8 bf[4];
      const int brow = nf * 16 + l16;
      const char* bp = (const char*)Bbuf[cur] + brow * 256;
#pragma unroll
      for (int ks = 0; ks < 4; ++ks)
        bf[ks] = *(const short8*)(bp + ((ks * 64 + lh * 16) ^ ((brow & 7) << 4)));
#pragma unroll
      for (int mf = 0; mf < 4; ++mf) cbuf[nf & 1][mf] = ZERO;
      __builtin_amdgcn_s_setprio(1);
#pragma unroll
      for (int ks = 0; ks < 4; ++ks)  // ks-outer: 4 independent acc chains
#pragma unroll
        for (int mf = 0; mf < 4; ++mf)
          cbuf[nf & 1][mf] = __builtin_amdgcn_mfma_f32_16x16x32_bf16(
              af[mf][ks], bf[ks], cbuf[nf & 1][mf], 0, 0, 0);
      __builtin_amdgcn_s_setprio(0);
      // deferred exp: process PREVIOUS group's C (operands long ready)
      if (nf > 0) EXPBLOCK(nf - 1, (nf ^ 1) & 1);
    }
    EXPBLOCK(3, 1);  // epilogue: last group's exp
    __syncthreads();
  }
  if (do_cs && w == 0) {  // flush last tile (ct=15 -> buf 1)
    float v = (csbuf[1][0][l] + csbuf[1][1][l]) + (csbuf[1][2][l] + csbuf[1][3][l]);
    R21p[(size_t)rb * NROWS + cr * 1024 + 15 * 64 + l] = v;
  }

  // row-sums: reduce over the 16 col-lanes; A-row = mf*16 + lh*4 + r [m89]
#pragma unroll
  for (int m = 1; m <= 8; m <<= 1)
#pragma unroll
    for (int mf = 0; mf < 4; ++mf)
#pragma unroll
      for (int r = 0; r < 4; ++r) rs[mf][r] += __shfl_xor(rs[mf][r], m, 64);
  if (l16 == 0) {
    float* base = &Rp[(size_t)(pass * 8 + cr) * NROWS + rb * 256 + w * 64];
#pragma unroll
    for (int mf = 0; mf < 4; ++mf) {
      f32x4 v = {rs[mf][0], rs[mf][1], rs[mf][2], rs[mf][3]};
      *(f32x4*)(base + mf * 16 + lh * 4) = v;
    }
  }
}

// ---------------------------------------------------------------------------
// Kernel 3: per-row denominators (coalesced partial reduction).
// ---------------------------------------------------------------------------
__global__ __launch_bounds__(256) void denom_kernel(
    const float* __restrict__ Rp, const float* __restrict__ R21p,
    float* __restrict__ dlog) {
  const int i = blockIdx.x * 256 + threadIdx.x;
  const float E2 = 7.3890560989306495f;
  float r11 = 0.f, r22 = 0.f, r12 = 0.f, r21 = 0.f;
#pragma unroll
  for (int k = 0; k < 8; ++k) r11 += Rp[(size_t)k * NROWS + i];
#pragma unroll
  for (int k = 8; k < 16; ++k) r22 += Rp[(size_t)k * NROWS + i];
#pragma unroll
  for (int k = 16; k < 24; ++k) r12 += Rp[(size_t)k * NROWS + i];
#pragma unroll
  for (int rb = 0; rb < 32; ++rb) r21 += R21p[(size_t)rb * NROWS + i];
  dlog[i] = 0.5f * (logf(r11 + r12 - E2) + logf(r22 + r21 - E2));
}

// ---------------------------------------------------------------------------
// Kernel 4: diag dots + per-row loss + block partials (deterministic).
// loss_i = -ln2 * dot_i + dlog[i]   (dot of alpha-scaled rows = 2*log2(e)*s)
// ---------------------------------------------------------------------------
__global__ __launch_bounds__(256) void loss_kernel(
    const unsigned short* __restrict__ hs1, const unsigned short* __restrict__ hs2,
    const float* __restrict__ dlog, float* __restrict__ partial) {
  const int tid = threadIdx.x;
  const int l = tid & 63;
  const int wv = tid >> 6;
  const int gw = blockIdx.x * 4 + wv;  // 0..1023
  const float LN2 = 0.6931471805599453f;
  float acc = 0.f;
  for (int t = 0; t < 8; ++t) {
    int i = gw * 8 + t;
    int off = (((l << 2) & ~15) ^ ((i & 7) << 4)) | ((l & 3) << 2);
    unsigned int a = *(const unsigned int*)((const char*)hs1 + (size_t)i * 256 + off);
    unsigned int b = *(const unsigned int*)((const char*)hs2 + (size_t)i * 256 + off);
    float p = bf2f(a & 0xffffu) * bf2f(b & 0xffffu) + bf2f(a >> 16) * bf2f(b >> 16);
#pragma unroll
    for (int m = 1; m < 64; m <<= 1) p += __shfl_xor(p, m, 64);
    if (l == 0) acc += -LN2 * p + dlog[i];
  }
  __shared__ float wacc[4];
  if (l == 0) wacc[wv] = acc;
  __syncthreads();
  if (tid == 0) partial[blockIdx.x] = wacc[0] + wacc[1] + wacc[2] + wacc[3];
}

__global__ void loss_final(const float* __restrict__ partial, float* __restrict__ outp) {
  const int t = threadIdx.x;
  float v = partial[t] + partial[t + 64] + partial[t + 128] + partial[t + 192];
#pragma unroll
  for (int m = 1; m < 64; m <<= 1) v += __shfl_xor(v, m, 64);
  if (t == 0) outp[0] = v * (1.0f / 8192.0f);
}

// ---------------------------------------------------------------------------
extern "C" void kernel_launch(void* const* d_in, const int* in_sizes, int n_in,
                              void* d_out, int out_size, void* d_ws, size_t ws_size,
                              hipStream_t stream) {
  const float* z1 = (const float*)d_in[0];
  const float* z2 = (const float*)d_in[1];
  const float* w1 = (const float*)d_in[2];
  const float* b1 = (const float*)d_in[3];
  const float* w2 = (const float*)d_in[4];
  const float* b2 = (const float*)d_in[5];
  char* ws = (char*)d_ws;
  unsigned short* hs1 = (unsigned short*)ws;                              // 2 MB
  unsigned short* hs2 = (unsigned short*)(ws + (size_t)2 * 1024 * 1024);  // 2 MB
  float* Rp = (float*)(ws + (size_t)4 * 1024 * 1024);                     // 24*8192*4 = 768 KB
  float* R21p = (float*)(ws + (size_t)4 * 1024 * 1024 + 768 * 1024);      // 32*8192*4 = 1 MB
  float* dlog = (float*)(ws + (size_t)6 * 1024 * 1024);                   // 32 KB
  float* partial = (float*)(ws + (size_t)6 * 1024 * 1024 + 64 * 1024);    // 1 KB
  float* outp = (float*)d_out;

  proj_kernel<<<dim3(256), dim3(256), 0, stream>>>(z1, z2, w1, b1, w2, b2, hs1, hs2);
  gram_kernel<<<dim3(768), dim3(256), 0, stream>>>(hs1, hs2, Rp, R21p);
  denom_kernel<<<dim3(32), dim3(256), 0, stream>>>(Rp, R21p, dlog);
  loss_kernel<<<dim3(256), dim3(256), 0, stream>>>(hs1, hs2, dlog, partial);
  loss_final<<<dim3(1), dim3(64), 0, stream>>>(partial, outp);
}

// Round 10
// 87.623 us; speedup vs baseline: 5.7479x; 1.0135x over previous
//
#include <hip/hip_runtime.h>
#include <stdint.h>

typedef __attribute__((ext_vector_type(4))) float f32x4;
typedef __attribute__((ext_vector_type(8))) short short8;

#define NROWS 8192

static __device__ __forceinline__ unsigned int f2bf(float f) {
  unsigned int u = __float_as_uint(f);
  return (u + 0x7fffu + ((u >> 16) & 1u)) >> 16;  // RNE
}
static __device__ __forceinline__ float bf2f(unsigned int h) {
  return __uint_as_float(h << 16);
}
static __device__ __forceinline__ float fast_exp2(float x) {
  // args bounded (|x| < 3): raw v_exp_f32, skip OCML range/denorm handling
#if __has_builtin(__builtin_amdgcn_exp2f)
  return __builtin_amdgcn_exp2f(x);
#else
  float r;
  asm("v_exp_f32 %0, %1" : "=v"(r) : "v"(x));
  return r;
#endif
}

// hs layout: per 256B row r, 16B chunk c stored at chunk position c ^ (r&7).
// Linear global->LDS DMA then yields the bank-conflict-free swizzled LDS
// layout for ds_read_b128 fragments (G4 / m201 pre-swizzled-source pattern).

// ---------------------------------------------------------------------------
// Kernel 1: projection fc2(elu(fc1(z))) + L2-normalize, bf16 MFMA + f32
// epilogue. 256 blocks x 256 threads; block = 64 rows of one z. Output rows
// pre-scaled by sqrt(2*log2 e) so Gram MFMA output is the exp2 argument,
// written in the swizzled global layout.
// ---------------------------------------------------------------------------
__global__ __launch_bounds__(256) void proj_kernel(
    const float* __restrict__ z1, const float* __restrict__ z2,
    const float* __restrict__ w1g, const float* __restrict__ b1g,
    const float* __restrict__ w2g, const float* __restrict__ b2g,
    unsigned short* __restrict__ hs1, unsigned short* __restrict__ hs2) {
  __shared__ unsigned short W1[128 * 128];
  __shared__ unsigned short W2[128 * 128];
  __shared__ unsigned short X[64 * 128];
  const int tid = threadIdx.x;
  const int w = tid >> 6, l = tid & 63, l16 = l & 15, lh = l >> 4;
  const int zi = blockIdx.x >> 7, rb = blockIdx.x & 127;
  const float* zg = (zi ? z2 : z1) + (size_t)rb * 64 * 128;
  unsigned short* outp = (zi ? hs2 : hs1) + (size_t)rb * 64 * 128;

  float bias1[8], bias2[8];
#pragma unroll
  for (int nf = 0; nf < 8; ++nf) {
    bias1[nf] = b1g[nf * 16 + l16];
    bias2[nf] = b2g[nf * 16 + l16];
  }

#pragma unroll
  for (int t = 0; t < 16; ++t) {
    int c = tid + t * 256;
    int r = c >> 5, q = c & 31;
    int off = r * 256 + ((((q >> 1) ^ (r & 7)) << 4) | ((q & 1) << 3));
    f32x4 va = *(const f32x4*)&w1g[c * 4];
    f32x4 vb = *(const f32x4*)&w2g[c * 4];
    uint2 pa, pb;
    pa.x = f2bf(va.x) | (f2bf(va.y) << 16);
    pa.y = f2bf(va.z) | (f2bf(va.w) << 16);
    pb.x = f2bf(vb.x) | (f2bf(vb.y) << 16);
    pb.y = f2bf(vb.z) | (f2bf(vb.w) << 16);
    *(uint2*)((char*)W1 + off) = pa;
    *(uint2*)((char*)W2 + off) = pb;
  }
#pragma unroll
  for (int t = 0; t < 8; ++t) {
    int c = tid + t * 256;
    int r = c >> 5, q = c & 31;
    int off = r * 256 + ((((q >> 1) ^ (r & 7)) << 4) | ((q & 1) << 3));
    f32x4 v = *(const f32x4*)&zg[c * 4];
    uint2 p;
    p.x = f2bf(v.x) | (f2bf(v.y) << 16);
    p.y = f2bf(v.z) | (f2bf(v.w) << 16);
    *(uint2*)((char*)X + off) = p;
  }
  __syncthreads();

  const f32x4 ZERO = {0.f, 0.f, 0.f, 0.f};
  const int arow = w * 16 + l16;

  short8 a1[4];
#pragma unroll
  for (int ks = 0; ks < 4; ++ks)
    a1[ks] = *(const short8*)((const char*)X + arow * 256 +
                              ((ks * 64 + lh * 16) ^ ((arow & 7) << 4)));
  f32x4 h[8];
#pragma unroll
  for (int nf = 0; nf < 8; ++nf) {
    const int brow = nf * 16 + l16;
    const char* bp = (const char*)W1 + brow * 256;
    f32x4 c = ZERO;
#pragma unroll
    for (int ks = 0; ks < 4; ++ks) {
      short8 b = *(const short8*)(bp + ((ks * 64 + lh * 16) ^ ((brow & 7) << 4)));
      c = __builtin_amdgcn_mfma_f32_16x16x32_bf16(a1[ks], b, c, 0, 0, 0);
    }
#pragma unroll
    for (int r = 0; r < 4; ++r) {
      float x = c[r] + bias1[nf];
      c[r] = x > 0.f ? x : expm1f(x);
    }
    h[nf] = c;
  }
  __syncthreads();

#pragma unroll
  for (int nf = 0; nf < 8; ++nf)
#pragma unroll
    for (int r = 0; r < 4; ++r) {
      int row = w * 16 + lh * 4 + r;
      int c2 = (nf * 16 + l16) * 2;
      int off = row * 256 + ((c2 & ~15) ^ ((row & 7) << 4)) + (c2 & 15);
      *(unsigned short*)((char*)X + off) = (unsigned short)f2bf(h[nf][r]);
    }
  __syncthreads();

  short8 a2[4];
#pragma unroll
  for (int ks = 0; ks < 4; ++ks)
    a2[ks] = *(const short8*)((const char*)X + arow * 256 +
                              ((ks * 64 + lh * 16) ^ ((arow & 7) << 4)));
  f32x4 o[8];
#pragma unroll
  for (int nf = 0; nf < 8; ++nf) {
    const int brow = nf * 16 + l16;
    const char* bp = (const char*)W2 + brow * 256;
    f32x4 c = ZERO;
#pragma unroll
    for (int ks = 0; ks < 4; ++ks) {
      short8 b = *(const short8*)(bp + ((ks * 64 + lh * 16) ^ ((brow & 7) << 4)));
      c = __builtin_amdgcn_mfma_f32_16x16x32_bf16(a2[ks], b, c, 0, 0, 0);
    }
#pragma unroll
    for (int r = 0; r < 4; ++r) c[r] += bias2[nf];
    o[nf] = c;
  }

  float ss[4] = {0.f, 0.f, 0.f, 0.f};
#pragma unroll
  for (int nf = 0; nf < 8; ++nf)
#pragma unroll
    for (int r = 0; r < 4; ++r) ss[r] += o[nf][r] * o[nf][r];
#pragma unroll
  for (int m = 1; m <= 8; m <<= 1)
#pragma unroll
    for (int r = 0; r < 4; ++r) ss[r] += __shfl_xor(ss[r], m, 64);
  float sc[4];
#pragma unroll
  for (int r = 0; r < 4; ++r)
    sc[r] = 1.6986436005760381f / fmaxf(sqrtf(ss[r]), 1e-12f);

#pragma unroll
  for (int nf = 0; nf < 8; ++nf)
#pragma unroll
    for (int r = 0; r < 4; ++r) {
      int row = w * 16 + lh * 4 + r;
      int c2 = (nf * 16 + l16) * 2;
      int off = row * 256 + ((c2 & ~15) ^ ((row & 7) << 4)) + (c2 & 15);
      *(unsigned short*)((char*)outp + off) = (unsigned short)f2bf(o[nf][r] * sc[r]);
    }
}

// ---------------------------------------------------------------------------
// Kernel 2: fused Gram + exp2 + row-sum (+ col-sum in pass 2).
// 3 passes: 0 -> R11, 1 -> R22, 2 -> z1 x z2 (R12 row-sums + R21 col-sums).
// Grid 768 = 3 passes x 32 rowblocks(256) x 8 col-ranges(1024), 256 threads
// (4 waves, 3 blocks/CU). __launch_bounds__(256,3): cap 170, af[4][4]
// resident (caps <=128 spill af — rounds 2/5/7).
// ROUND-10 CHANGE (T3/T4-lite): triple-buffered B with prefetch distance 2 +
// counted vmcnt + RAW s_barrier. __syncthreads drained vmcnt(0) every iter,
// serially absorbing the DMA latency with only 3 waves/SIMD to hide it
// (r9: MFMA busy == theoretical 20µs but wall 70µs => stall-bound).
// Steady state: wait vmcnt(4) (own S(ct) done, S(ct+1) in flight), barrier,
// issue STAGE(ct+2). Writes of buf[(ct+2)%3] race-safe: its last readers
// (compute ct-1) all passed barrier(ct). Deferred-exp + setprio kept (r9).
// ---------------------------------------------------------------------------
#define EXPBLOCK(G, SLOT)                                             \
  {                                                                   \
    float cs = 0.f;                                                   \
    _Pragma("unroll") for (int mf = 0; mf < 4; ++mf)                  \
        _Pragma("unroll") for (int r = 0; r < 4; ++r) {               \
      float e = fast_exp2(cbuf[SLOT][mf][r]);                         \
      rs[mf][r] += e;                                                 \
      if (do_cs) cs += e;                                             \
    }                                                                 \
    if (do_cs) {                                                      \
      cs += __shfl_xor(cs, 16, 64);                                   \
      cs += __shfl_xor(cs, 32, 64);                                   \
      if (lh == 0) csbuf[ct & 1][w][(G)*16 + l16] = cs;               \
    }                                                                 \
  }

__global__ __launch_bounds__(256, 3) void gram_kernel(
    const unsigned short* __restrict__ hs1, const unsigned short* __restrict__ hs2,
    float* __restrict__ Rp,     // [24][8192] (pass*8+cr) row-sum partials
    float* __restrict__ R21p) { // [32][8192] col-sum partials (pass 2)
  __shared__ unsigned short Bbuf[3][64 * 128];  // 48KB, prefetch depth 2
  __shared__ float csbuf[2][4][64];

  const int tid = threadIdx.x;
  const int w = tid >> 6, l = tid & 63, l16 = l & 15, lh = l >> 4;
  const int pass = blockIdx.x >> 8;
  const int idx = blockIdx.x & 255;
  const int rb = idx >> 3;  // 32 rowblocks of 256 rows
  const int cr = idx & 7;   // 8 col-ranges of 1024 cols

  const unsigned short* Ag = (pass == 1) ? hs2 : hs1;
  const unsigned short* Bg = (pass == 0) ? hs1 : hs2;
  const char* bbase = (const char*)Bg + (size_t)cr * (1024 * 256);
  const bool do_cs = (pass == 2);

  auto STAGE = [&](int buf, int ct) {
#pragma unroll
    for (int s = 0; s < 4; ++s) {
      const char* src = bbase + (size_t)ct * 16384 + s * 4096 + tid * 16;
      char* dst = (char*)Bbuf[buf] + s * 4096 + w * 1024;  // wave-uniform base
      __builtin_amdgcn_global_load_lds(
          (const __attribute__((address_space(1))) void*)src,
          (__attribute__((address_space(3))) void*)dst, 16, 0, 0);
    }
  };

  STAGE(0, 0);
  STAGE(1, 1);

  short8 af[4][4];  // 64 rows per wave, resident (64 VGPRs)
  {
    const char* abase = (const char*)Ag + ((size_t)rb * 256 + w * 64) * 256;
#pragma unroll
    for (int mf = 0; mf < 4; ++mf) {
      int row = mf * 16 + l16;
#pragma unroll
      for (int ks = 0; ks < 4; ++ks)
        af[mf][ks] = *(const short8*)(abase + row * 256 +
                                      ((ks * 64 + lh * 16) ^ ((row & 7) << 4)));
    }
  }

  float rs[4][4];
#pragma unroll
  for (int mf = 0; mf < 4; ++mf)
#pragma unroll
    for (int r = 0; r < 4; ++r) rs[mf][r] = 0.f;
  const f32x4 ZERO = {0.f, 0.f, 0.f, 0.f};

  int brd = 0;  // read buffer = ct % 3
  for (int ct = 0; ct < 16; ++ct) {
    // counted wait: own S(ct) complete, S(ct+1) stays in flight (never 0
    // mid-loop); then RAW barrier (no compiler vmcnt(0) drain).
    if (ct < 15)
      asm volatile("s_waitcnt vmcnt(4)" ::: "memory");
    else
      asm volatile("s_waitcnt vmcnt(0)" ::: "memory");
    __builtin_amdgcn_s_barrier();
    if (ct + 2 < 16) {
      const int bwr = (brd >= 1) ? brd - 1 : 2;  // (ct+2)%3
      STAGE(bwr, ct + 2);
    }
    if (do_cs && w == 0 && ct > 0) {  // flush prev tile's col-sums (overlaps)
      float v = (csbuf[(ct - 1) & 1][0][l] + csbuf[(ct - 1) & 1][1][l]) +
                (csbuf[(ct - 1) & 1][2][l] + csbuf[(ct - 1) & 1][3][l]);
      R21p[(size_t)rb * NROWS + cr * 1024 + (ct - 1) * 64 + l] = v;
    }
    f32x4 cbuf[2][4];
    const char* bufp = (const char*)Bbuf[brd];
#pragma unroll
    for (int nf = 0; nf < 4; ++nf) {
      short8 bf[4];
      const int brow = nf * 16 + l16;
      const char* bp = bufp + brow * 256;
#pragma unroll
      for (int ks = 0; ks < 4; ++ks)
        bf[ks] = *(const short8*)(bp + ((ks * 64 + lh * 16) ^ ((brow & 7) << 4)));
#pragma unroll
      for (int mf = 0; mf < 4; ++mf) cbuf[nf & 1][mf] = ZERO;
      __builtin_amdgcn_s_setprio(1);
#pragma unroll
      for (int ks = 0; ks < 4; ++ks)  // ks-outer: 4 independent acc chains
#pragma unroll
        for (int mf = 0; mf < 4; ++mf)
          cbuf[nf & 1][mf] = __builtin_amdgcn_mfma_f32_16x16x32_bf16(
              af[mf][ks], bf[ks], cbuf[nf & 1][mf], 0, 0, 0);
      __builtin_amdgcn_s_setprio(0);
      // deferred exp: process PREVIOUS group's C (operands long ready)
      if (nf > 0) EXPBLOCK(nf - 1, (nf ^ 1) & 1);
    }
    EXPBLOCK(3, 1);  // last group's exp
    brd = (brd == 2) ? 0 : brd + 1;
  }
  __syncthreads();  // csbuf[1] writes (compute ct=15) visible to w0

  if (do_cs && w == 0) {  // flush last tile (ct=15 -> slot 1)
    float v = (csbuf[1][0][l] + csbuf[1][1][l]) + (csbuf[1][2][l] + csbuf[1][3][l]);
    R21p[(size_t)rb * NROWS + cr * 1024 + 15 * 64 + l] = v;
  }

  // row-sums: reduce over the 16 col-lanes; A-row = mf*16 + lh*4 + r [m89]
#pragma unroll
  for (int m = 1; m <= 8; m <<= 1)
#pragma unroll
    for (int mf = 0; mf < 4; ++mf)
#pragma unroll
      for (int r = 0; r < 4; ++r) rs[mf][r] += __shfl_xor(rs[mf][r], m, 64);
  if (l16 == 0) {
    float* base = &Rp[(size_t)(pass * 8 + cr) * NROWS + rb * 256 + w * 64];
#pragma unroll
    for (int mf = 0; mf < 4; ++mf) {
      f32x4 v = {rs[mf][0], rs[mf][1], rs[mf][2], rs[mf][3]};
      *(f32x4*)(base + mf * 16 + lh * 4) = v;
    }
  }
}

// ---------------------------------------------------------------------------
// Kernel 3: per-row denominators (coalesced partial reduction).
// ---------------------------------------------------------------------------
__global__ __launch_bounds__(256) void denom_kernel(
    const float* __restrict__ Rp, const float* __restrict__ R21p,
    float* __restrict__ dlog) {
  const int i = blockIdx.x * 256 + threadIdx.x;
  const float E2 = 7.3890560989306495f;
  float r11 = 0.f, r22 = 0.f, r12 = 0.f, r21 = 0.f;
#pragma unroll
  for (int k = 0; k < 8; ++k) r11 += Rp[(size_t)k * NROWS + i];
#pragma unroll
  for (int k = 8; k < 16; ++k) r22 += Rp[(size_t)k * NROWS + i];
#pragma unroll
  for (int k = 16; k < 24; ++k) r12 += Rp[(size_t)k * NROWS + i];
#pragma unroll
  for (int rb = 0; rb < 32; ++rb) r21 += R21p[(size_t)rb * NROWS + i];
  dlog[i] = 0.5f * (logf(r11 + r12 - E2) + logf(r22 + r21 - E2));
}

// ---------------------------------------------------------------------------
// Kernel 4: diag dots + per-row loss + block partials (deterministic).
// loss_i = -ln2 * dot_i + dlog[i]   (dot of alpha-scaled rows = 2*log2(e)*s)
// ---------------------------------------------------------------------------
__global__ __launch_bounds__(256) void loss_kernel(
    const unsigned short* __restrict__ hs1, const unsigned short* __restrict__ hs2,
    const float* __restrict__ dlog, float* __restrict__ partial) {
  const int tid = threadIdx.x;
  const int l = tid & 63;
  const int wv = tid >> 6;
  const int gw = blockIdx.x * 4 + wv;  // 0..1023
  const float LN2 = 0.6931471805599453f;
  float acc = 0.f;
  for (int t = 0; t < 8; ++t) {
    int i = gw * 8 + t;
    int off = (((l << 2) & ~15) ^ ((i & 7) << 4)) | ((l & 3) << 2);
    unsigned int a = *(const unsigned int*)((const char*)hs1 + (size_t)i * 256 + off);
    unsigned int b = *(const unsigned int*)((const char*)hs2 + (size_t)i * 256 + off);
    float p = bf2f(a & 0xffffu) * bf2f(b & 0xffffu) + bf2f(a >> 16) * bf2f(b >> 16);
#pragma unroll
    for (int m = 1; m < 64; m <<= 1) p += __shfl_xor(p, m, 64);
    if (l == 0) acc += -LN2 * p + dlog[i];
  }
  __shared__ float wacc[4];
  if (l == 0) wacc[wv] = acc;
  __syncthreads();
  if (tid == 0) partial[blockIdx.x] = wacc[0] + wacc[1] + wacc[2] + wacc[3];
}

__global__ void loss_final(const float* __restrict__ partial, float* __restrict__ outp) {
  const int t = threadIdx.x;
  float v = partial[t] + partial[t + 64] + partial[t + 128] + partial[t + 192];
#pragma unroll
  for (int m = 1; m < 64; m <<= 1) v += __shfl_xor(v, m, 64);
  if (t == 0) outp[0] = v * (1.0f / 8192.0f);
}

// ---------------------------------------------------------------------------
extern "C" void kernel_launch(void* const* d_in, const int* in_sizes, int n_in,
                              void* d_out, int out_size, void* d_ws, size_t ws_size,
                              hipStream_t stream) {
  const float* z1 = (const float*)d_in[0];
  const float* z2 = (const float*)d_in[1];
  const float* w1 = (const float*)d_in[2];
  const float* b1 = (const float*)d_in[3];
  const float* w2 = (const float*)d_in[4];
  const float* b2 = (const float*)d_in[5];
  char* ws = (char*)d_ws;
  unsigned short* hs1 = (unsigned short*)ws;                              // 2 MB
  unsigned short* hs2 = (unsigned short*)(ws + (size_t)2 * 1024 * 1024);  // 2 MB
  float* Rp = (float*)(ws + (size_t)4 * 1024 * 1024);                     // 24*8192*4 = 768 KB
  float* R21p = (float*)(ws + (size_t)4 * 1024 * 1024 + 768 * 1024);      // 32*8192*4 = 1 MB
  float* dlog = (float*)(ws + (size_t)6 * 1024 * 1024);                   // 32 KB
  float* partial = (float*)(ws + (size_t)6 * 1024 * 1024 + 64 * 1024);    // 1 KB
  float* outp = (float*)d_out;

  proj_kernel<<<dim3(256), dim3(256), 0, stream>>>(z1, z2, w1, b1, w2, b2, hs1, hs2);
  gram_kernel<<<dim3(768), dim3(256), 0, stream>>>(hs1, hs2, Rp, R21p);
  denom_kernel<<<dim3(32), dim3(256), 0, stream>>>(Rp, R21p, dlog);
  loss_kernel<<<dim3(256), dim3(256), 0, stream>>>(hs1, hs2, dlog, partial);
  loss_final<<<dim3(1), dim3(64), 0, stream>>>(partial, outp);
}